// Round 7
// baseline (1415.167 us; speedup 1.0000x reference)
//
#include <hip/hip_runtime.h>

#define N_NODES 20000
#define E_EDGES 640000
#define R_REL   64
#define B_BASES 16

// W_rel[r][i][o] = sum_b w_comp[r][b] * weight[b][i][o]   (f32)
// 64*128*128 = 1,048,576 outputs, one thread each.
__global__ void k_wrel(const float* weight, const float* w_comp, float* W_rel)
{
    int idx = blockIdx.x * 256 + threadIdx.x;
    int r  = idx >> 14;
    int io = idx & 16383;
    float acc = 0.0f;
    for (int b = 0; b < B_BASES; b++) {
        acc += w_comp[r * B_BASES + b] * weight[b * 16384 + io];
    }
    W_rel[idx] = acc;
}

// zero agg (2,560,000 f32) and counts (64 ints)
__global__ void k_zero(float* agg, int* counts)
{
    int idx = blockIdx.x * 256 + threadIdx.x;
    if (idx < N_NODES * 128) agg[idx] = 0.0f;
    if (idx < R_REL) counts[idx] = 0;
}

// per-block LDS histogram of etypes -> global counts[64]
__global__ void k_hist(const int* etypes, int* counts)
{
    __shared__ int h[R_REL];
    int t = threadIdx.x;
    if (t < R_REL) h[t] = 0;
    __syncthreads();
    int e = blockIdx.x * 256 + t;            // E is a multiple of 256
    atomicAdd(&h[etypes[e]], 1);
    __syncthreads();
    if (t < R_REL && h[t] != 0) atomicAdd(&counts[t], h[t]);
}

// serial scan: offsets (edge base per relation), cursor copy, chunk offsets
__global__ void k_scan(const int* counts, int* offsets, int* cursor, int* co)
{
    if (threadIdx.x == 0) {
        int run = 0, c = 0;
        for (int r = 0; r < R_REL; r++) {
            offsets[r] = run; cursor[r] = run; co[r] = c;
            run += counts[r];
            c   += (counts[r] + 63) >> 6;
        }
        offsets[R_REL] = run; co[R_REL] = c;
    }
}

// bucket scatter: perm[] = edge ids grouped by etype
__global__ void k_scatter(const int* etypes, int* cursor, int* perm)
{
    __shared__ int h[R_REL];
    __shared__ int base[R_REL];
    int t = threadIdx.x;
    if (t < R_REL) h[t] = 0;
    __syncthreads();
    int e = blockIdx.x * 256 + t;
    int et = etypes[e];
    int rank = atomicAdd(&h[et], 1);
    __syncthreads();
    if (t < R_REL && h[t] != 0) base[t] = atomicAdd(&cursor[t], h[t]);
    __syncthreads();
    perm[base[et] + rank] = e;
}

// One block per 64-edge chunk of one relation. 256 threads.
// Stage W_rel[r] (128x128 f32, 64 KB) + 64 gathered x rows (32 KB) in LDS.
// Thread t: o-quad q = t&31 (columns q*4..q*4+3), edge set e = (t>>5) + 8k.
// Inner loop: 1 float4 W read + 8 x reads per 32 FMA.
__global__ void k_edge(const float* x, const float* W_rel, const float* norm,
                       const int* src, const int* dst, const int* perm,
                       const int* offsets, const int* co, float* agg)
{
    __shared__ float4 WfS[4096];     // [i][o/4] = 128 x 32
    __shared__ float4 xsS[2048];     // [e][i/4] = 64 x 32
    __shared__ int coS[R_REL + 1];
    __shared__ int srcS[64], dstS[64];
    __shared__ float normS[64];
    int t = threadIdx.x, bid = blockIdx.x;
    if (t <= R_REL) coS[t] = co[t];
    __syncthreads();
    if (bid >= coS[R_REL]) return;
    int r = 0;
    while (bid >= coS[r + 1]) r++;                 // uniform per block
    int e0 = offsets[r] + (bid - coS[r]) * 64;
    int cnt = offsets[r + 1] - e0;
    if (cnt > 64) cnt = 64;

    if (t < 64) {
        if (t < cnt) {
            int eid = perm[e0 + t];
            srcS[t] = src[eid]; dstS[t] = dst[eid]; normS[t] = norm[eid];
        } else { srcS[t] = 0; dstS[t] = 0; normS[t] = 0.0f; }
    }
    {   // stage W_rel[r]: 4096 float4, coalesced
        const float4* Wsrc = (const float4*)(W_rel + r * 16384);
        for (int p = 0; p < 16; p++) WfS[p * 256 + t] = Wsrc[p * 256 + t];
    }
    __syncthreads();
    {   // gather x rows: 2048 float4
        for (int p = 0; p < 8; p++) {
            int idx = p * 256 + t;
            int e = idx >> 5, c = idx & 31;
            const float4* xsrc = (const float4*)(x + srcS[e] * 128);
            xsS[idx] = xsrc[c];
        }
    }
    __syncthreads();

    const float* xsf = (const float*)xsS;
    int q  = t & 31;
    int eb = t >> 5;
    float4 acc[8];
    for (int k = 0; k < 8; k++) { acc[k].x = 0.0f; acc[k].y = 0.0f; acc[k].z = 0.0f; acc[k].w = 0.0f; }
    for (int i = 0; i < 128; i++) {
        float4 wv = WfS[i * 32 + q];
        for (int k = 0; k < 8; k++) {
            float xv = xsf[(eb + 8 * k) * 128 + i];
            acc[k].x += xv * wv.x;
            acc[k].y += xv * wv.y;
            acc[k].z += xv * wv.z;
            acc[k].w += xv * wv.w;
        }
    }
    for (int k = 0; k < 8; k++) {
        int e = eb + 8 * k;
        if (e < cnt) {
            float nrm = normS[e];
            float* row = agg + dstS[e] * 128 + q * 4;
            atomicAdd(row + 0, acc[k].x * nrm);
            atomicAdd(row + 1, acc[k].y * nrm);
            atomicAdd(row + 2, acc[k].z * nrm);
            atomicAdd(row + 3, acc[k].w * nrm);
        }
    }
}

// one block (128 threads) per node:
// out[n][o] = relu(agg[n][o] + bias[o] + sum_i x[n][i]*loop_w[i][o]), f32 store
__global__ void k_out(const float* x, const float* loop_w, const float* agg,
                      const float* bias, float* out)
{
    __shared__ float xrow[128];
    int n = blockIdx.x;
    int o = threadIdx.x;
    xrow[o] = x[n * 128 + o];
    __syncthreads();
    float acc = 0.0f;
    for (int i = 0; i < 128; i++) {
        acc += xrow[i] * loop_w[i * 128 + o];
    }
    float val = acc + agg[n * 128 + o] + bias[o];
    if (val < 0.0f) val = 0.0f;
    out[n * 128 + o] = val;
}

extern "C" void kernel_launch(void* const* d_in, const int* in_sizes, int n_in,
                              void* d_out, int out_size, void* d_ws, size_t ws_size,
                              hipStream_t stream)
{
    const float* x      = (const float*)d_in[0];
    const float* weight = (const float*)d_in[1];
    const float* w_comp = (const float*)d_in[2];
    const float* h_bias = (const float*)d_in[3];
    const float* loop_w = (const float*)d_in[4];
    const float* norm   = (const float*)d_in[5];
    const int* src    = (const int*)d_in[6];
    const int* dst    = (const int*)d_in[7];
    const int* etypes = (const int*)d_in[8];
    float* out = (float*)d_out;

    // workspace: W_rel 4 MB | agg 10.24 MB | perm 2.56 MB | small arrays
    char* ws = (char*)d_ws;
    float* W_rel = (float*)ws;
    size_t off = (size_t)R_REL * 16384 * sizeof(float);
    float* agg = (float*)(ws + off); off += (size_t)N_NODES * 128 * sizeof(float);
    int* perm  = (int*)(ws + off);   off += (size_t)E_EDGES * sizeof(int);
    int* counts  = (int*)(ws + off); off += 64 * sizeof(int);
    int* offsets = (int*)(ws + off); off += 68 * sizeof(int);
    int* cursor  = (int*)(ws + off); off += 64 * sizeof(int);
    int* co      = (int*)(ws + off); off += 68 * sizeof(int);

    k_wrel<<<(R_REL * 16384) / 256, 256, 0, stream>>>(weight, w_comp, W_rel);
    k_zero<<<(N_NODES * 128) / 256, 256, 0, stream>>>(agg, counts);
    k_hist<<<E_EDGES / 256, 256, 0, stream>>>(etypes, counts);
    k_scan<<<1, 64, 0, stream>>>(counts, offsets, cursor, co);
    k_scatter<<<E_EDGES / 256, 256, 0, stream>>>(etypes, cursor, perm);
    k_edge<<<E_EDGES / 64 + R_REL, 256, 0, stream>>>(
        x, W_rel, norm, src, dst, perm, offsets, co, agg);
    k_out<<<N_NODES, 128, 0, stream>>>(x, loop_w, agg, h_bias, out);
}

// Round 8
// 688.092 us; speedup vs baseline: 2.0567x; 2.0567x over previous
//
#include <hip/hip_runtime.h>

#define N_NODES 20000
#define E_EDGES 640000
#define R_REL   64
#define B_BASES 16

__device__ inline float bf2f(unsigned short v) {
    unsigned int u = ((unsigned int)v) << 16;
    return __uint_as_float(u);
}
__device__ inline unsigned short f2bf(float f) {
    unsigned int u = __float_as_uint(f);
    unsigned int r = (u + 0x7FFF + ((u >> 16) & 1)) >> 16;  // RNE
    return (unsigned short)r;
}

// W_rel[r][i][o] = sum_b w_comp[r][b] * weight[b][i][o]   (f32)
__global__ void k_wrel(const float* weight, const float* w_comp, float* W_rel)
{
    int idx = blockIdx.x * 256 + threadIdx.x;
    int r  = idx >> 14;
    int io = idx & 16383;
    float acc = 0.0f;
    for (int b = 0; b < B_BASES; b++)
        acc += w_comp[r * B_BASES + b] * weight[b * 16384 + io];
    W_rel[idx] = acc;
}

// zero agg (2.56M f32), counts (64), counts2 (20000)
__global__ void k_zero(float* agg, int* counts, int* counts2)
{
    int idx = blockIdx.x * 256 + threadIdx.x;
    if (idx < N_NODES * 128) agg[idx] = 0.0f;
    if (idx < R_REL) counts[idx] = 0;
    if (idx < N_NODES) counts2[idx] = 0;
}

// per-block LDS histogram of etypes -> counts[64]
__global__ void k_hist(const int* etypes, int* counts)
{
    __shared__ int h[R_REL];
    int t = threadIdx.x;
    if (t < R_REL) h[t] = 0;
    __syncthreads();
    int e = blockIdx.x * 256 + t;
    atomicAdd(&h[etypes[e]], 1);
    __syncthreads();
    if (t < R_REL && h[t] != 0) atomicAdd(&counts[t], h[t]);
}

// serial 64-entry scan: offsets, cursor, chunk offsets
__global__ void k_scan(const int* counts, int* offsets, int* cursor, int* co)
{
    if (threadIdx.x == 0) {
        int run = 0, c = 0;
        for (int r = 0; r < R_REL; r++) {
            offsets[r] = run; cursor[r] = run; co[r] = c;
            run += counts[r];
            c   += (counts[r] + 63) >> 6;
        }
        offsets[R_REL] = run; co[R_REL] = c;
    }
}

// bucket scatter: perm[] = edge ids grouped by etype
__global__ void k_scatter(const int* etypes, int* cursor, int* perm)
{
    __shared__ int h[R_REL];
    __shared__ int base[R_REL];
    int t = threadIdx.x;
    if (t < R_REL) h[t] = 0;
    __syncthreads();
    int e = blockIdx.x * 256 + t;
    int et = etypes[e];
    int rank = atomicAdd(&h[et], 1);
    __syncthreads();
    if (t < R_REL && h[t] != 0) base[t] = atomicAdd(&cursor[t], h[t]);
    __syncthreads();
    perm[base[et] + rank] = e;
}

// dst histogram: counts2[20000]
__global__ void k_hist2(const int* dst, int* counts2)
{
    int e = blockIdx.x * 256 + threadIdx.x;
    atomicAdd(&counts2[dst[e]], 1);
}

// single-block parallel scan over 20000 dst counts -> off2, cursor2
__global__ void k_scan2(const int* counts2, int* off2, int* cursor2)
{
    __shared__ int part[256];
    int t = threadIdx.x;
    int lo = t * 79;
    int hi = lo + 79; if (hi > N_NODES) hi = N_NODES;
    int s = 0;
    for (int i = lo; i < hi; i++) s += counts2[i];
    part[t] = s;
    __syncthreads();
    for (int d = 1; d < 256; d <<= 1) {
        int v = (t >= d) ? part[t - d] : 0;
        __syncthreads();
        part[t] += v;
        __syncthreads();
    }
    int run = part[t] - s;                  // exclusive prefix
    for (int i = lo; i < hi; i++) {
        off2[i] = run; cursor2[i] = run;
        run += counts2[i];
    }
    if (t == 255) off2[N_NODES] = run;
}

// eidx2[dst-sorted slot] = etype-order message position p
__global__ void k_rank2(const int* perm, const int* dst, int* cursor2, int* eidx2)
{
    int p = blockIdx.x * 256 + threadIdx.x;
    int eid = perm[p];
    int q = atomicAdd(&cursor2[dst[eid]], 1);
    eidx2[q] = p;
}

// ---- Phase A (big path): per 64-edge chunk, K-split GEMM, bf16 msg stores ----
// LDS: W half 32KB + x half 16KB (+misc) ~= 49.5KB -> 3 blocks/CU.
__global__ void k_edge_msg(const float* x, const float* W_rel, const float* norm,
                           const int* src, const int* perm,
                           const int* offsets, const int* co,
                           unsigned short* msg)
{
    __shared__ float4 WfS[2048];     // [i=64][o/4=32]
    __shared__ float4 xsS[1024];     // [e=64][i/4=16]
    __shared__ int coS[R_REL + 1];
    __shared__ int srcS[64];
    __shared__ float normS[64];
    int t = threadIdx.x, bid = blockIdx.x;
    if (t <= R_REL) coS[t] = co[t];
    __syncthreads();
    if (bid >= coS[R_REL]) return;
    int r = 0;
    while (bid >= coS[r + 1]) r++;
    int e0 = offsets[r] + (bid - coS[r]) * 64;
    int cnt = offsets[r + 1] - e0;
    if (cnt > 64) cnt = 64;
    if (t < 64) {
        if (t < cnt) {
            int eid = perm[e0 + t];
            srcS[t] = src[eid]; normS[t] = norm[eid];
        } else { srcS[t] = 0; normS[t] = 0.0f; }
    }

    const float* xsf = (const float*)xsS;
    int q  = t & 31;
    int eb = t >> 5;
    float4 acc[8];
    for (int k = 0; k < 8; k++) { acc[k].x = 0.f; acc[k].y = 0.f; acc[k].z = 0.f; acc[k].w = 0.f; }

    for (int h = 0; h < 2; h++) {
        __syncthreads();   // srcS ready (h=0) / previous compute done (h=1)
        const float4* Wsrc = (const float4*)(W_rel + r * 16384 + h * 8192);
        for (int p = 0; p < 8; p++) WfS[p * 256 + t] = Wsrc[p * 256 + t];
        for (int p = 0; p < 4; p++) {
            int idx = p * 256 + t;
            int e = idx >> 4, c = idx & 15;
            xsS[idx] = ((const float4*)(x + srcS[e] * 128 + h * 64))[c];
        }
        __syncthreads();
        for (int i = 0; i < 64; i++) {
            float4 wv = WfS[i * 32 + q];
            for (int k = 0; k < 8; k++) {
                float xv = xsf[(eb + 8 * k) * 64 + i];
                acc[k].x += xv * wv.x;
                acc[k].y += xv * wv.y;
                acc[k].z += xv * wv.z;
                acc[k].w += xv * wv.w;
            }
        }
    }
    for (int k = 0; k < 8; k++) {
        int e = eb + 8 * k;
        if (e < cnt) {
            float nrm = normS[e];
            unsigned int p0 = (unsigned int)f2bf(acc[k].x * nrm)
                            | ((unsigned int)f2bf(acc[k].y * nrm) << 16);
            unsigned int p1 = (unsigned int)f2bf(acc[k].z * nrm)
                            | ((unsigned int)f2bf(acc[k].w * nrm) << 16);
            unsigned int* row = (unsigned int*)(msg + (size_t)(e0 + e) * 128) + q * 2;
            row[0] = p0; row[1] = p1;
        }
    }
}

// ---- Phase B (big path): per node, gather msg rows + self-loop + bias + relu ----
__global__ void k_out2(const float* x, const float* loop_w,
                       const unsigned short* msg, const int* eidx2,
                       const int* off2, const float* bias, float* out)
{
    __shared__ float xrow[128];
    int n = blockIdx.x;
    int o = threadIdx.x;
    xrow[o] = x[n * 128 + o];
    __syncthreads();
    float acc = 0.0f;
    for (int i = 0; i < 128; i++)
        acc += xrow[i] * loop_w[i * 128 + o];
    int m0 = off2[n], m1 = off2[n + 1];
    for (int j = m0; j < m1; j++) {
        int p = eidx2[j];
        acc += bf2f(msg[(size_t)p * 128 + o]);
    }
    float val = acc + bias[o];
    if (val < 0.0f) val = 0.0f;
    out[n * 128 + o] = val;
}

// ---- Fallback path (small ws): K-split + atomics into agg ----
__global__ void k_edge_atomic(const float* x, const float* W_rel, const float* norm,
                              const int* src, const int* dst, const int* perm,
                              const int* offsets, const int* co, float* agg)
{
    __shared__ float4 WfS[2048];
    __shared__ float4 xsS[1024];
    __shared__ int coS[R_REL + 1];
    __shared__ int srcS[64], dstS[64];
    __shared__ float normS[64];
    int t = threadIdx.x, bid = blockIdx.x;
    if (t <= R_REL) coS[t] = co[t];
    __syncthreads();
    if (bid >= coS[R_REL]) return;
    int r = 0;
    while (bid >= coS[r + 1]) r++;
    int e0 = offsets[r] + (bid - coS[r]) * 64;
    int cnt = offsets[r + 1] - e0;
    if (cnt > 64) cnt = 64;
    if (t < 64) {
        if (t < cnt) {
            int eid = perm[e0 + t];
            srcS[t] = src[eid]; dstS[t] = dst[eid]; normS[t] = norm[eid];
        } else { srcS[t] = 0; dstS[t] = 0; normS[t] = 0.0f; }
    }
    const float* xsf = (const float*)xsS;
    int q  = t & 31;
    int eb = t >> 5;
    float4 acc[8];
    for (int k = 0; k < 8; k++) { acc[k].x = 0.f; acc[k].y = 0.f; acc[k].z = 0.f; acc[k].w = 0.f; }
    for (int h = 0; h < 2; h++) {
        __syncthreads();
        const float4* Wsrc = (const float4*)(W_rel + r * 16384 + h * 8192);
        for (int p = 0; p < 8; p++) WfS[p * 256 + t] = Wsrc[p * 256 + t];
        for (int p = 0; p < 4; p++) {
            int idx = p * 256 + t;
            int e = idx >> 4, c = idx & 15;
            xsS[idx] = ((const float4*)(x + srcS[e] * 128 + h * 64))[c];
        }
        __syncthreads();
        for (int i = 0; i < 64; i++) {
            float4 wv = WfS[i * 32 + q];
            for (int k = 0; k < 8; k++) {
                float xv = xsf[(eb + 8 * k) * 64 + i];
                acc[k].x += xv * wv.x;
                acc[k].y += xv * wv.y;
                acc[k].z += xv * wv.z;
                acc[k].w += xv * wv.w;
            }
        }
    }
    for (int k = 0; k < 8; k++) {
        int e = eb + 8 * k;
        if (e < cnt) {
            float nrm = normS[e];
            float* row = agg + dstS[e] * 128 + q * 4;
            atomicAdd(row + 0, acc[k].x * nrm);
            atomicAdd(row + 1, acc[k].y * nrm);
            atomicAdd(row + 2, acc[k].z * nrm);
            atomicAdd(row + 3, acc[k].w * nrm);
        }
    }
}

__global__ void k_out(const float* x, const float* loop_w, const float* agg,
                      const float* bias, float* out)
{
    __shared__ float xrow[128];
    int n = blockIdx.x;
    int o = threadIdx.x;
    xrow[o] = x[n * 128 + o];
    __syncthreads();
    float acc = 0.0f;
    for (int i = 0; i < 128; i++)
        acc += xrow[i] * loop_w[i * 128 + o];
    float val = acc + agg[n * 128 + o] + bias[o];
    if (val < 0.0f) val = 0.0f;
    out[n * 128 + o] = val;
}

extern "C" void kernel_launch(void* const* d_in, const int* in_sizes, int n_in,
                              void* d_out, int out_size, void* d_ws, size_t ws_size,
                              hipStream_t stream)
{
    const float* x      = (const float*)d_in[0];
    const float* weight = (const float*)d_in[1];
    const float* w_comp = (const float*)d_in[2];
    const float* h_bias = (const float*)d_in[3];
    const float* loop_w = (const float*)d_in[4];
    const float* norm   = (const float*)d_in[5];
    const int* src    = (const int*)d_in[6];
    const int* dst    = (const int*)d_in[7];
    const int* etypes = (const int*)d_in[8];
    float* out = (float*)d_out;

    char* ws = (char*)d_ws;
    size_t off = 0;
    float* W_rel = (float*)(ws + off); off += (size_t)R_REL * 16384 * 4;
    float* agg   = (float*)(ws + off); off += (size_t)N_NODES * 128 * 4;
    int* perm    = (int*)(ws + off);   off += (size_t)E_EDGES * 4;
    int* counts  = (int*)(ws + off);   off += 64 * 4;
    int* offsets = (int*)(ws + off);   off += 68 * 4;
    int* cursor  = (int*)(ws + off);   off += 64 * 4;
    int* co      = (int*)(ws + off);   off += 68 * 4;
    int* counts2 = (int*)(ws + off);   off += (size_t)N_NODES * 4;
    int* off2    = (int*)(ws + off);   off += (size_t)(N_NODES + 1) * 4;
    int* cursor2 = (int*)(ws + off);   off += (size_t)N_NODES * 4;
    int* eidx2   = (int*)(ws + off);   off += (size_t)E_EDGES * 4;
    unsigned short* msg = (unsigned short*)(ws + off);
    size_t need_big = off + (size_t)E_EDGES * 128 * 2;
    int big = (ws_size >= need_big) ? 1 : 0;

    k_wrel<<<(R_REL * 16384) / 256, 256, 0, stream>>>(weight, w_comp, W_rel);
    k_zero<<<(N_NODES * 128) / 256, 256, 0, stream>>>(agg, counts, counts2);
    k_hist<<<E_EDGES / 256, 256, 0, stream>>>(etypes, counts);
    k_scan<<<1, 64, 0, stream>>>(counts, offsets, cursor, co);
    k_scatter<<<E_EDGES / 256, 256, 0, stream>>>(etypes, cursor, perm);

    if (big) {
        k_hist2<<<E_EDGES / 256, 256, 0, stream>>>(dst, counts2);
        k_scan2<<<1, 256, 0, stream>>>(counts2, off2, cursor2);
        k_rank2<<<E_EDGES / 256, 256, 0, stream>>>(perm, dst, cursor2, eidx2);
        k_edge_msg<<<E_EDGES / 64 + R_REL, 256, 0, stream>>>(
            x, W_rel, norm, src, perm, offsets, co, msg);
        k_out2<<<N_NODES, 128, 0, stream>>>(x, loop_w, msg, eidx2, off2, h_bias, out);
    } else {
        k_edge_atomic<<<E_EDGES / 64 + R_REL, 256, 0, stream>>>(
            x, W_rel, norm, src, dst, perm, offsets, co, agg);
        k_out<<<N_NODES, 128, 0, stream>>>(x, loop_w, agg, h_bias, out);
    }
}

// Round 9
// 679.178 us; speedup vs baseline: 2.0836x; 1.0131x over previous
//
#include <hip/hip_runtime.h>

#define N_NODES 20000
#define E_EDGES 640000
#define R_REL   64
#define B_BASES 16

__device__ inline float bf2f(unsigned short v) {
    unsigned int u = ((unsigned int)v) << 16;
    return __uint_as_float(u);
}
__device__ inline unsigned short f2bf(float f) {
    unsigned int u = __float_as_uint(f);
    unsigned int r = (u + 0x7FFF + ((u >> 16) & 1)) >> 16;  // RNE
    return (unsigned short)r;
}

// W_rel[r][i][o] = sum_b w_comp[r][b] * weight[b][i][o]   (f32)
__global__ void k_wrel(const float* weight, const float* w_comp, float* W_rel)
{
    int idx = blockIdx.x * 256 + threadIdx.x;
    int r  = idx >> 14;
    int io = idx & 16383;
    float acc = 0.0f;
    for (int b = 0; b < B_BASES; b++)
        acc += w_comp[r * B_BASES + b] * weight[b * 16384 + io];
    W_rel[idx] = acc;
}

// zero agg (fallback), counts (64), counts2 (20000)
__global__ void k_zero(float* agg, int* counts, int* counts2)
{
    int idx = blockIdx.x * 256 + threadIdx.x;
    if (idx < N_NODES * 128) agg[idx] = 0.0f;
    if (idx < R_REL) counts[idx] = 0;
    if (idx < N_NODES) counts2[idx] = 0;
}

// per-block LDS histogram of etypes -> counts[64]
__global__ void k_hist(const int* etypes, int* counts)
{
    __shared__ int h[R_REL];
    int t = threadIdx.x;
    if (t < R_REL) h[t] = 0;
    __syncthreads();
    int e = blockIdx.x * 256 + t;
    atomicAdd(&h[etypes[e]], 1);
    __syncthreads();
    if (t < R_REL && h[t] != 0) atomicAdd(&counts[t], h[t]);
}

// serial 64-entry scan: offsets, cursor, chunk offsets
__global__ void k_scan(const int* counts, int* offsets, int* cursor, int* co)
{
    if (threadIdx.x == 0) {
        int run = 0, c = 0;
        for (int r = 0; r < R_REL; r++) {
            offsets[r] = run; cursor[r] = run; co[r] = c;
            run += counts[r];
            c   += (counts[r] + 63) >> 6;
        }
        offsets[R_REL] = run; co[R_REL] = c;
    }
}

// bucket scatter: perm[] = edge ids grouped by etype
__global__ void k_scatter(const int* etypes, int* cursor, int* perm)
{
    __shared__ int h[R_REL];
    __shared__ int base[R_REL];
    int t = threadIdx.x;
    if (t < R_REL) h[t] = 0;
    __syncthreads();
    int e = blockIdx.x * 256 + t;
    int et = etypes[e];
    int rank = atomicAdd(&h[et], 1);
    __syncthreads();
    if (t < R_REL && h[t] != 0) base[t] = atomicAdd(&cursor[t], h[t]);
    __syncthreads();
    perm[base[et] + rank] = e;
}

// dst histogram: counts2[20000]
__global__ void k_hist2(const int* dst, int* counts2)
{
    int e = blockIdx.x * 256 + threadIdx.x;
    atomicAdd(&counts2[dst[e]], 1);
}

// single-block parallel scan over 20000 dst counts -> off2, cursor2
__global__ void k_scan2(const int* counts2, int* off2, int* cursor2)
{
    __shared__ int part[256];
    int t = threadIdx.x;
    int lo = t * 79;
    int hi = lo + 79; if (hi > N_NODES) hi = N_NODES;
    int s = 0;
    for (int i = lo; i < hi; i++) s += counts2[i];
    part[t] = s;
    __syncthreads();
    for (int d = 1; d < 256; d <<= 1) {
        int v = (t >= d) ? part[t - d] : 0;
        __syncthreads();
        part[t] += v;
        __syncthreads();
    }
    int run = part[t] - s;                  // exclusive prefix
    for (int i = lo; i < hi; i++) {
        off2[i] = run; cursor2[i] = run;
        run += counts2[i];
    }
    if (t == 255) off2[N_NODES] = run;
}

// pos2[etype-order position p] = dst-sorted slot
__global__ void k_rank2(const int* perm, const int* dst, int* cursor2, int* pos2)
{
    int p = blockIdx.x * 256 + threadIdx.x;
    int eid = perm[p];
    int slot = atomicAdd(&cursor2[dst[eid]], 1);
    pos2[p] = slot;
}

// ---- Phase A: per 64-edge chunk, K-split GEMM, bf16 msg stored at dst-sorted slot ----
__global__ void k_edge_msg(const float* x, const float* W_rel, const float* norm,
                           const int* src, const int* perm, const int* pos2,
                           const int* offsets, const int* co,
                           unsigned short* msg)
{
    __shared__ float4 WfS[2048];     // [i=64][o/4=32]
    __shared__ float4 xsS[1024];     // [e=64][i/4=16]
    __shared__ int coS[R_REL + 1];
    __shared__ int srcS[64];
    __shared__ float normS[64];
    int t = threadIdx.x, bid = blockIdx.x;
    if (t <= R_REL) coS[t] = co[t];
    __syncthreads();
    if (bid >= coS[R_REL]) return;
    int r = 0;
    while (bid >= coS[r + 1]) r++;
    int e0 = offsets[r] + (bid - coS[r]) * 64;
    int cnt = offsets[r + 1] - e0;
    if (cnt > 64) cnt = 64;
    if (t < 64) {
        if (t < cnt) {
            int eid = perm[e0 + t];
            srcS[t] = src[eid]; normS[t] = norm[eid];
        } else { srcS[t] = 0; normS[t] = 0.0f; }
    }

    const float* xsf = (const float*)xsS;
    int q  = t & 31;
    int eb = t >> 5;
    float4 acc[8];
    for (int k = 0; k < 8; k++) { acc[k].x = 0.f; acc[k].y = 0.f; acc[k].z = 0.f; acc[k].w = 0.f; }

    for (int h = 0; h < 2; h++) {
        __syncthreads();
        const float4* Wsrc = (const float4*)(W_rel + r * 16384 + h * 8192);
        for (int p = 0; p < 8; p++) WfS[p * 256 + t] = Wsrc[p * 256 + t];
        for (int p = 0; p < 4; p++) {
            int idx = p * 256 + t;
            int e = idx >> 4, c = idx & 15;
            xsS[idx] = ((const float4*)(x + srcS[e] * 128 + h * 64))[c];
        }
        __syncthreads();
        for (int i = 0; i < 64; i++) {
            float4 wv = WfS[i * 32 + q];
            for (int k = 0; k < 8; k++) {
                float xv = xsf[(eb + 8 * k) * 64 + i];
                acc[k].x += xv * wv.x;
                acc[k].y += xv * wv.y;
                acc[k].z += xv * wv.z;
                acc[k].w += xv * wv.w;
            }
        }
    }
    for (int k = 0; k < 8; k++) {
        int e = eb + 8 * k;
        if (e < cnt) {
            float nrm = normS[e];
            int slot = pos2[e0 + e];
            unsigned int p0 = (unsigned int)f2bf(acc[k].x * nrm)
                            | ((unsigned int)f2bf(acc[k].y * nrm) << 16);
            unsigned int p1 = (unsigned int)f2bf(acc[k].z * nrm)
                            | ((unsigned int)f2bf(acc[k].w * nrm) << 16);
            unsigned int* row = (unsigned int*)(msg + (size_t)slot * 128) + q * 2;
            row[0] = p0; row[1] = p1;
        }
    }
}

// ---- self-loop GEMM: out[n][o] = x[n]@loop_w[:,o] + bias[o]  (f32, no relu yet) ----
__global__ void k_selfgemm(const float* x, const float* loop_w, const float* bias,
                           float* out)
{
    __shared__ float4 WfS[2048];     // [i=64][o/4=32]
    __shared__ float4 xsS[1024];     // [n=64][i/4=16]
    int t = threadIdx.x, bid = blockIdx.x;
    int n0 = bid * 64;
    const float* xsf = (const float*)xsS;
    int q  = t & 31;
    int eb = t >> 5;
    float4 acc[8];
    for (int k = 0; k < 8; k++) { acc[k].x = 0.f; acc[k].y = 0.f; acc[k].z = 0.f; acc[k].w = 0.f; }
    for (int h = 0; h < 2; h++) {
        __syncthreads();
        const float4* Wsrc = (const float4*)(loop_w + h * 8192);
        for (int p = 0; p < 8; p++) WfS[p * 256 + t] = Wsrc[p * 256 + t];
        for (int p = 0; p < 4; p++) {
            int idx = p * 256 + t;
            int e = idx >> 4, c = idx & 15;
            int n = n0 + e; if (n >= N_NODES) n = N_NODES - 1;
            xsS[idx] = ((const float4*)(x + n * 128 + h * 64))[c];
        }
        __syncthreads();
        for (int i = 0; i < 64; i++) {
            float4 wv = WfS[i * 32 + q];
            for (int k = 0; k < 8; k++) {
                float xv = xsf[(eb + 8 * k) * 64 + i];
                acc[k].x += xv * wv.x;
                acc[k].y += xv * wv.y;
                acc[k].z += xv * wv.z;
                acc[k].w += xv * wv.w;
            }
        }
    }
    float4 b4 = *((const float4*)(bias + q * 4));
    for (int k = 0; k < 8; k++) {
        int n = n0 + eb + 8 * k;
        if (n < N_NODES) {
            float4 v;
            v.x = acc[k].x + b4.x;
            v.y = acc[k].y + b4.y;
            v.z = acc[k].z + b4.z;
            v.w = acc[k].w + b4.w;
            *((float4*)(out + (size_t)n * 128 + q * 4)) = v;
        }
    }
}

// ---- msg reduction: out[n][o] = relu(out[n][o] + sum contiguous msg rows) ----
__global__ void k_msgsum(const unsigned short* msg, const int* off2, float* out)
{
    int n = blockIdx.x;
    int o = threadIdx.x;        // 128 threads
    int m0 = off2[n], m1 = off2[n + 1];
    float acc = 0.0f;
    for (int j = m0; j < m1; j++)
        acc += bf2f(msg[(size_t)j * 128 + o]);
    float val = out[(size_t)n * 128 + o] + acc;
    if (val < 0.0f) val = 0.0f;
    out[(size_t)n * 128 + o] = val;
}

// ---- Fallback path (small ws): K-split + atomics into agg ----
__global__ void k_edge_atomic(const float* x, const float* W_rel, const float* norm,
                              const int* src, const int* dst, const int* perm,
                              const int* offsets, const int* co, float* agg)
{
    __shared__ float4 WfS[2048];
    __shared__ float4 xsS[1024];
    __shared__ int coS[R_REL + 1];
    __shared__ int srcS[64], dstS[64];
    __shared__ float normS[64];
    int t = threadIdx.x, bid = blockIdx.x;
    if (t <= R_REL) coS[t] = co[t];
    __syncthreads();
    if (bid >= coS[R_REL]) return;
    int r = 0;
    while (bid >= coS[r + 1]) r++;
    int e0 = offsets[r] + (bid - coS[r]) * 64;
    int cnt = offsets[r + 1] - e0;
    if (cnt > 64) cnt = 64;
    if (t < 64) {
        if (t < cnt) {
            int eid = perm[e0 + t];
            srcS[t] = src[eid]; dstS[t] = dst[eid]; normS[t] = norm[eid];
        } else { srcS[t] = 0; dstS[t] = 0; normS[t] = 0.0f; }
    }
    const float* xsf = (const float*)xsS;
    int q  = t & 31;
    int eb = t >> 5;
    float4 acc[8];
    for (int k = 0; k < 8; k++) { acc[k].x = 0.f; acc[k].y = 0.f; acc[k].z = 0.f; acc[k].w = 0.f; }
    for (int h = 0; h < 2; h++) {
        __syncthreads();
        const float4* Wsrc = (const float4*)(W_rel + r * 16384 + h * 8192);
        for (int p = 0; p < 8; p++) WfS[p * 256 + t] = Wsrc[p * 256 + t];
        for (int p = 0; p < 4; p++) {
            int idx = p * 256 + t;
            int e = idx >> 4, c = idx & 15;
            xsS[idx] = ((const float4*)(x + srcS[e] * 128 + h * 64))[c];
        }
        __syncthreads();
        for (int i = 0; i < 64; i++) {
            float4 wv = WfS[i * 32 + q];
            for (int k = 0; k < 8; k++) {
                float xv = xsf[(eb + 8 * k) * 64 + i];
                acc[k].x += xv * wv.x;
                acc[k].y += xv * wv.y;
                acc[k].z += xv * wv.z;
                acc[k].w += xv * wv.w;
            }
        }
    }
    for (int k = 0; k < 8; k++) {
        int e = eb + 8 * k;
        if (e < cnt) {
            float nrm = normS[e];
            float* row = agg + dstS[e] * 128 + q * 4;
            atomicAdd(row + 0, acc[k].x * nrm);
            atomicAdd(row + 1, acc[k].y * nrm);
            atomicAdd(row + 2, acc[k].z * nrm);
            atomicAdd(row + 3, acc[k].w * nrm);
        }
    }
}

__global__ void k_out(const float* x, const float* loop_w, const float* agg,
                      const float* bias, float* out)
{
    __shared__ float xrow[128];
    int n = blockIdx.x;
    int o = threadIdx.x;
    xrow[o] = x[n * 128 + o];
    __syncthreads();
    float acc = 0.0f;
    for (int i = 0; i < 128; i++)
        acc += xrow[i] * loop_w[i * 128 + o];
    float val = acc + agg[n * 128 + o] + bias[o];
    if (val < 0.0f) val = 0.0f;
    out[n * 128 + o] = val;
}

extern "C" void kernel_launch(void* const* d_in, const int* in_sizes, int n_in,
                              void* d_out, int out_size, void* d_ws, size_t ws_size,
                              hipStream_t stream)
{
    const float* x      = (const float*)d_in[0];
    const float* weight = (const float*)d_in[1];
    const float* w_comp = (const float*)d_in[2];
    const float* h_bias = (const float*)d_in[3];
    const float* loop_w = (const float*)d_in[4];
    const float* norm   = (const float*)d_in[5];
    const int* src    = (const int*)d_in[6];
    const int* dst    = (const int*)d_in[7];
    const int* etypes = (const int*)d_in[8];
    float* out = (float*)d_out;

    char* ws = (char*)d_ws;
    size_t off = 0;
    float* W_rel = (float*)(ws + off); off += (size_t)R_REL * 16384 * 4;
    float* agg   = (float*)(ws + off); off += (size_t)N_NODES * 128 * 4;
    int* perm    = (int*)(ws + off);   off += (size_t)E_EDGES * 4;
    int* counts  = (int*)(ws + off);   off += 64 * 4;
    int* offsets = (int*)(ws + off);   off += 68 * 4;
    int* cursor  = (int*)(ws + off);   off += 64 * 4;
    int* co      = (int*)(ws + off);   off += 68 * 4;
    int* counts2 = (int*)(ws + off);   off += (size_t)N_NODES * 4;
    int* off2    = (int*)(ws + off);   off += (size_t)(N_NODES + 1) * 4;
    int* cursor2 = (int*)(ws + off);   off += (size_t)N_NODES * 4;
    int* pos2    = (int*)(ws + off);   off += (size_t)E_EDGES * 4;
    unsigned short* msg = (unsigned short*)(ws + off);
    size_t need_big = off + (size_t)E_EDGES * 128 * 2;
    int big = (ws_size >= need_big) ? 1 : 0;

    k_wrel<<<(R_REL * 16384) / 256, 256, 0, stream>>>(weight, w_comp, W_rel);
    k_zero<<<(N_NODES * 128) / 256, 256, 0, stream>>>(agg, counts, counts2);
    k_hist<<<E_EDGES / 256, 256, 0, stream>>>(etypes, counts);
    k_scan<<<1, 64, 0, stream>>>(counts, offsets, cursor, co);
    k_scatter<<<E_EDGES / 256, 256, 0, stream>>>(etypes, cursor, perm);

    if (big) {
        k_hist2<<<E_EDGES / 256, 256, 0, stream>>>(dst, counts2);
        k_scan2<<<1, 256, 0, stream>>>(counts2, off2, cursor2);
        k_rank2<<<E_EDGES / 256, 256, 0, stream>>>(perm, dst, cursor2, pos2);
        k_edge_msg<<<E_EDGES / 64 + R_REL, 256, 0, stream>>>(
            x, W_rel, norm, src, perm, pos2, offsets, co, msg);
        k_selfgemm<<<(N_NODES + 63) / 64, 256, 0, stream>>>(x, loop_w, h_bias, out);
        k_msgsum<<<N_NODES, 128, 0, stream>>>(msg, off2, out);
    } else {
        k_edge_atomic<<<E_EDGES / 64 + R_REL, 256, 0, stream>>>(
            x, W_rel, norm, src, dst, perm, offsets, co, agg);
        k_out<<<N_NODES, 128, 0, stream>>>(x, loop_w, agg, h_bias, out);
    }
}